// Round 9
// baseline (74.961 us; speedup 1.0000x reference)
//
#include <hip/hip_runtime.h>
#include <math.h>

// SubsetOperator (Gumbel top-K relaxation), B=4096 rows, N=8192 cols, K=8, TAU=1.
// Exp-domain transform: w = exp(s+g-M0); per iter: oh = w*inv; kh += oh;
// w = fma(-oh, w, w). One exp per element; K-loop is pure packed mul/fma + reduce.
//
// R9 structure: persistent blocks, RPB=8 rows each (grid 512). Phase-overlap
// analysis of R4-R8: dur was pinned at 69us = HBM floor (43us) + VALU (25us)
// SERIALIZED — co-resident blocks stay phase-locked (homogeneous durations),
// so loads and compute never overlap. Fix: in-block software pipeline — issue
// next row's loads into stage registers right after consuming the current
// stage, then run the (VMEM-free) K-loop while they stream. Only row 0's load
// is exposed. Occupancy is irrelevant (proved R5/R6/R7), so ~150 VGPR is fine.
// NO __launch_bounds__ min-waves (R7: VGPR cap -> scratch spill disaster).

#define BROWS 4096
#define NCOLS 8192
#define KITER 8
#define THREADS 256
#define RPB 8
#define GRID (BROWS / RPB)        // 512
#define VECS 8                    // 8 x float4 = 32 elems/thread/row
#define NWAVES (THREADS / 64)     // 4
#define M0 24.0f

typedef float f32x4 __attribute__((ext_vector_type(4)));
typedef float f32x2 __attribute__((ext_vector_type(2)));

__global__ __launch_bounds__(THREADS)
void subset_op_kernel(const float* __restrict__ scores,
                      const float* __restrict__ g,
                      float* __restrict__ out) {
  const int tid = threadIdx.x;
  const int lane = tid & 63;
  const int wave = tid >> 6;
  const long long row0 = (long long)blockIdx.x * RPB;

  __shared__ float red[2][NWAVES];

  // ---- stage registers: raw scores + g for one row (issued early) ----
  f32x4 ss[VECS], sg[VECS];
  {
    const float* sp = scores + row0 * NCOLS;
    const float* gp = g + row0 * NCOLS;
#pragma unroll
    for (int j = 0; j < VECS; ++j) {
      const int off = j * 1024 + tid * 4;
      ss[j] = *(const f32x4*)(sp + off);
      sg[j] = *(const f32x4*)(gp + off);
    }
  }

#pragma unroll 1
  for (int r = 0; r < RPB; ++r) {
    // ---- consume stage: w = exp(ss+sg-M0); kh = 0; first partial sum ----
    f32x2 w2[2 * VECS], kh2[2 * VECS];
    float sum = 0.0f;
#pragma unroll
    for (int j = 0; j < VECS; ++j) {
      const f32x4 t = ss[j] + sg[j];
      f32x2 lo, hi;
      lo.x = __expf(t.x - M0); lo.y = __expf(t.y - M0);
      hi.x = __expf(t.z - M0); hi.y = __expf(t.w - M0);
      w2[2 * j] = lo; w2[2 * j + 1] = hi;
      kh2[2 * j] = (f32x2){0.0f, 0.0f};
      kh2[2 * j + 1] = (f32x2){0.0f, 0.0f};
      sum += (lo.x + lo.y) + (hi.x + hi.y);
    }

    // ---- prefetch next row into stage regs; the K-loop below has zero VMEM
    //      ops, so these loads stream entirely behind it ----
    if (r + 1 < RPB) {
      const float* sp = scores + (row0 + r + 1) * NCOLS;
      const float* gp = g + (row0 + r + 1) * NCOLS;
#pragma unroll
      for (int j = 0; j < VECS; ++j) {
        const int off = j * 1024 + tid * 4;
        ss[j] = *(const f32x4*)(sp + off);
        sg[j] = *(const f32x4*)(gp + off);
      }
    }

    // ---- K iterations: block sum-reduce, packed multiplicative update ----
#pragma unroll 1
    for (int k = 0; k < KITER; ++k) {
      float ps = sum;
#pragma unroll
      for (int off = 32; off > 0; off >>= 1) ps += __shfl_xor(ps, off);
      if (lane == 0) red[k & 1][wave] = ps;
      __syncthreads();
      const f32x4 rv = *(const f32x4*)red[k & 1];
      const float tot = (rv.x + rv.y) + (rv.z + rv.w);
      const float inv = __builtin_amdgcn_rcpf(tot);   // ~1ulp; threshold 6e-2
      const f32x2 iv = {inv, inv};

      f32x2 s0 = {0.0f, 0.0f}, s1 = {0.0f, 0.0f};
      f32x2 s2 = {0.0f, 0.0f}, s3 = {0.0f, 0.0f};
#pragma unroll
      for (int j = 0; j < 2 * VECS; ++j) {
        const f32x2 oh = w2[j] * iv;                        // v_pk_mul_f32
        kh2[j] += oh;                                       // v_pk_add_f32
        w2[j] = __builtin_elementwise_fma(-oh, w2[j], w2[j]);  // v_pk_fma_f32
        if ((j & 3) == 0)      s0 += w2[j];
        else if ((j & 3) == 1) s1 += w2[j];
        else if ((j & 3) == 2) s2 += w2[j];
        else                   s3 += w2[j];
      }
      const f32x2 sv2 = (s0 + s1) + (s2 + s3);
      sum = sv2.x + sv2.y;
    }

    // ---- store khot for row r (nontemporal; drains behind next consume) ----
    {
      float* op = out + (row0 + r) * NCOLS;
#pragma unroll
      for (int j = 0; j < VECS; ++j) {
        const int off = j * 1024 + tid * 4;
        f32x4 v;
        v.x = kh2[2 * j].x;     v.y = kh2[2 * j].y;
        v.z = kh2[2 * j + 1].x; v.w = kh2[2 * j + 1].y;
        __builtin_nontemporal_store(v, (f32x4*)(op + off));
      }
    }
  }
}

extern "C" void kernel_launch(void* const* d_in, const int* in_sizes, int n_in,
                              void* d_out, int out_size, void* d_ws, size_t ws_size,
                              hipStream_t stream) {
  const float* scores = (const float*)d_in[0];
  const float* g = (const float*)d_in[1];
  float* out = (float*)d_out;
  (void)in_sizes; (void)n_in; (void)out_size; (void)d_ws; (void)ws_size;

  subset_op_kernel<<<GRID, THREADS, 0, stream>>>(scores, g, out);
}

// Round 10
// 68.978 us; speedup vs baseline: 1.0867x; 1.0867x over previous
//
#include <hip/hip_runtime.h>
#include <math.h>

// SubsetOperator (Gumbel top-K relaxation), B=4096 rows, N=8192 cols, K=8, TAU=1.
// Exp-domain transform: w = exp(s+g-M0); per iter: oh = w/sum; kh += oh;
// w = fma(-oh, w, w). One exp per element; K-loop is pure mul/fma + sum-reduce.
//
// FINAL (R8 structure). Session evidence:
//  - dur 69us = 402MB total data motion / 5.83 TB/s = 93% of D2D copy ceiling
//    (m13: 6.29 TB/s) -> memory-bound; VALU (~25us) hides under the stream.
//  - Occupancy is not the limiter (R5 29% ~ R4 54% ~ R6 75%: no correlation).
//  - In-block pipelining fails (R5 -1.5%, R9 -8%): memory already saturated,
//    extra VGPR state only subtracts.
//  - __launch_bounds__ min-waves clause is poison (R7: VGPR cap 64 -> scratch
//    spill, FETCH 131->424MB, 4x slowdown).
//  - 256 thr x 32 elems is VALU-minimal (1024-thr geometry quadruples reduce
//    cost: R6 regressed to 84us).

#define BROWS 4096
#define NCOLS 8192
#define KITER 8
#define THREADS 256
#define VECS 8                    // 8 x float4 = 32 elems/thread
#define NWAVES (THREADS / 64)     // 4
#define M0 24.0f

typedef float f32x4 __attribute__((ext_vector_type(4)));
typedef float f32x2 __attribute__((ext_vector_type(2)));

__global__ __launch_bounds__(THREADS)
void subset_op_kernel(const float* __restrict__ scores,
                      const float* __restrict__ g,
                      float* __restrict__ out) {
  const int tid = threadIdx.x;
  const int lane = tid & 63;
  const int wave = tid >> 6;
  const long long rbase = (long long)blockIdx.x * NCOLS;

  f32x2 w2[2 * VECS], kh2[2 * VECS];

  // ---- load, w = exp(s + g - M0); first partial sum ----
  float sum = 0.0f;
#pragma unroll
  for (int j = 0; j < VECS; ++j) {
    const int off = j * 1024 + tid * 4;
    const f32x4 sv = *(const f32x4*)(scores + rbase + off);
    const f32x4 gv = *(const f32x4*)(g + rbase + off);
    f32x2 lo, hi;
    lo.x = __expf(sv.x + gv.x - M0);
    lo.y = __expf(sv.y + gv.y - M0);
    hi.x = __expf(sv.z + gv.z - M0);
    hi.y = __expf(sv.w + gv.w - M0);
    w2[2 * j] = lo; w2[2 * j + 1] = hi;
    kh2[2 * j] = (f32x2){0.0f, 0.0f};
    kh2[2 * j + 1] = (f32x2){0.0f, 0.0f};
    sum += (lo.x + lo.y) + (hi.x + hi.y);
  }

  __shared__ float red[2][NWAVES];

  // ---- K iterations: block sum-reduce, packed multiplicative mask update ----
#pragma unroll 1
  for (int k = 0; k < KITER; ++k) {
    float ps = sum;
#pragma unroll
    for (int off = 32; off > 0; off >>= 1) ps += __shfl_xor(ps, off);
    if (lane == 0) red[k & 1][wave] = ps;
    __syncthreads();
    const f32x4 rv = *(const f32x4*)red[k & 1];
    const float tot = (rv.x + rv.y) + (rv.z + rv.w);
    const float inv = __builtin_amdgcn_rcpf(tot);   // ~1ulp, threshold is 6e-2
    const f32x2 iv = {inv, inv};

    f32x2 s0 = {0.0f, 0.0f}, s1 = {0.0f, 0.0f};
    f32x2 s2 = {0.0f, 0.0f}, s3 = {0.0f, 0.0f};
#pragma unroll
    for (int j = 0; j < 2 * VECS; ++j) {
      const f32x2 oh = w2[j] * iv;                       // v_pk_mul_f32
      kh2[j] += oh;                                      // v_pk_add_f32
      w2[j] = __builtin_elementwise_fma(-oh, w2[j], w2[j]);  // v_pk_fma_f32
      if ((j & 3) == 0)      s0 += w2[j];
      else if ((j & 3) == 1) s1 += w2[j];
      else if ((j & 3) == 2) s2 += w2[j];
      else                   s3 += w2[j];
    }
    const f32x2 sv2 = (s0 + s1) + (s2 + s3);
    sum = sv2.x + sv2.y;
  }

  // ---- store khot (nontemporal: written once, never re-read) ----
#pragma unroll
  for (int j = 0; j < VECS; ++j) {
    const int off = j * 1024 + tid * 4;
    f32x4 v;
    v.x = kh2[2 * j].x;     v.y = kh2[2 * j].y;
    v.z = kh2[2 * j + 1].x; v.w = kh2[2 * j + 1].y;
    __builtin_nontemporal_store(v, (f32x4*)(out + rbase + off));
  }
}

extern "C" void kernel_launch(void* const* d_in, const int* in_sizes, int n_in,
                              void* d_out, int out_size, void* d_ws, size_t ws_size,
                              hipStream_t stream) {
  const float* scores = (const float*)d_in[0];
  const float* g = (const float*)d_in[1];
  float* out = (float*)d_out;
  (void)in_sizes; (void)n_in; (void)out_size; (void)d_ws; (void)ws_size;

  subset_op_kernel<<<BROWS, THREADS, 0, stream>>>(scores, g, out);
}